// Round 6
// baseline (94.896 us; speedup 1.0000x reference)
//
#include <hip/hip_runtime.h>
#include <hip/hip_bf16.h>

// FastGRNN 2-layer (SRNN2). T=2048, B=256, D=32, H0=H1=64, O=35, brick=32.
// Layer 0: bf16 MFMA, fp32 accum + fp32 state. 1024 blocks x 256 thr (4 waves),
//   16 seqs/block, wave wn owns unit tile [16wn,16wn+16). 3 mfma/step/wave,
//   h via double-buffered XOR-swizzled bf16 LDS, 1 barrier/step, x prefetch 2.
//   VALU diet: packed bf16 cvt (v_cvt_pk_bf16_f32), 5-instr tanh, folded update.
// Layer 1: same MFMA structure, 16 blocks x 4 waves, 16 batch/block, 64 steps.
//   xW part computed on the fly from prefetched last0 rows (independent of h,
//   overlaps recurrence chain). Output projection fused at kernel end.

#define NB    64
#define BS    32
#define BATCH 256
#define D0    32
#define H     64
#define OUTD  35

typedef short  bf8   __attribute__((ext_vector_type(8)));
typedef float  f32x4 __attribute__((ext_vector_type(4)));

__device__ __forceinline__ float rcp_fast(float x) {
    return __builtin_amdgcn_rcpf(x);
}
// sigmoid: 4 VALU (mul, exp, add, rcp)
__device__ __forceinline__ float sigm(float x) {
    return rcp_fast(1.0f + __expf(-x));
}
// tanh(x) = 2*sigm(2x)-1 : 5 VALU, NaN-free (x=-inf -> rcp(inf)=0 -> -1)
__device__ __forceinline__ float tanh_fast(float x) {
    float q = rcp_fast(1.0f + __expf(-2.0f * x));
    return fmaf(2.0f, q, -1.0f);
}
__device__ __forceinline__ short f2bf(float f) {   // init-path only
    __hip_bfloat16 b = __float2bfloat16(f);
    return __builtin_bit_cast(short, b);
}
// packed pair -> v_cvt_pk_bf16_f32 (lo in bits[15:0]); memcpy because
// __hip_bfloat162 is not trivially copyable (bit_cast rejects it)
__device__ __forceinline__ unsigned pk2bf(float lo, float hi) {
    __hip_bfloat162 h2 = __float22bfloat162_rn(make_float2(lo, hi));
    unsigned r;
    __builtin_memcpy(&r, &h2, 4);
    return r;
}

union U4BF8 { unsigned u[4]; bf8 v; };

__global__ __launch_bounds__(256, 4) void l0_kernel(
    const float* __restrict__ x,     // [2048][256][32]
    const float* __restrict__ W,     // [32][64]
    const float* __restrict__ U,     // [64][64]
    const float* __restrict__ bg,
    const float* __restrict__ bu,
    const float* __restrict__ zeta,
    const float* __restrict__ nu,
    float* __restrict__ last0)       // [64*256][64]
{
    __shared__ unsigned char hb[2][16 * 128];   // bf16 h, bytes ^((seq&7)<<4)

    const int tid  = threadIdx.x;
    const int lane = tid & 63;
    const int wn   = __builtin_amdgcn_readfirstlane(tid >> 6);
    const int l15  = lane & 15;
    const int lg   = lane >> 4;

    const int brick     = blockIdx.x >> 4;
    const int batchbase = (blockIdx.x & 15) << 4;

    *reinterpret_cast<float2*>(&hb[0][tid * 8]) = make_float2(0.f, 0.f);

    bf8 Wb, Ub0, Ub1;
    const int ucol = wn * 16 + l15;
#pragma unroll
    for (int j = 0; j < 8; ++j) Wb[j]  = f2bf(W[(8 * lg + j) * H + ucol]);
#pragma unroll
    for (int j = 0; j < 8; ++j) Ub0[j] = f2bf(U[(8 * lg + j) * H + ucol]);
#pragma unroll
    for (int j = 0; j < 8; ++j) Ub1[j] = f2bf(U[(32 + 8 * lg + j) * H + ucol]);

    const float bgc = bg[ucol], buc = bu[ucol];
    const float zs  = sigm(zeta[0]);
    const float ns  = sigm(nu[0]);
    const float zns = zs + ns;

    float hc[4] = {0.f, 0.f, 0.f, 0.f};

    const float* xbase = x + ((size_t)(brick * BS) * BATCH + batchbase + l15) * D0 + 8 * lg;
    const size_t xstep = (size_t)BATCH * D0;

    float4 xa0 = reinterpret_cast<const float4*>(xbase)[0];
    float4 xa1 = reinterpret_cast<const float4*>(xbase)[1];
    float4 xn0 = reinterpret_cast<const float4*>(xbase + xstep)[0];
    float4 xn1 = reinterpret_cast<const float4*>(xbase + xstep)[1];

    // swizzled h-write byte offsets (loop-invariant)
    int woff[4];
#pragma unroll
    for (int r = 0; r < 4; ++r) {
        int s = 4 * lg + r;
        woff[r] = s * 128 + ((ucol * 2) ^ ((s & 7) << 4));
    }
    const int swz = (l15 & 7) << 4;

    __syncthreads();

    int cur = 0;
#pragma unroll 1
    for (int t = 0; t < BS; ++t) {
        const int tp = (t + 2 < BS) ? (t + 2) : (BS - 1);
        float4 p0 = reinterpret_cast<const float4*>(xbase + (size_t)tp * xstep)[0];
        float4 p1 = reinterpret_cast<const float4*>(xbase + (size_t)tp * xstep)[1];

        U4BF8 xp;
        xp.u[0] = pk2bf(xa0.x, xa0.y);
        xp.u[1] = pk2bf(xa0.z, xa0.w);
        xp.u[2] = pk2bf(xa1.x, xa1.y);
        xp.u[3] = pk2bf(xa1.z, xa1.w);

        f32x4 acc = {0.f, 0.f, 0.f, 0.f};
        acc = __builtin_amdgcn_mfma_f32_16x16x32_bf16(xp.v, Wb, acc, 0, 0, 0);

        const unsigned char* hr = &hb[cur][l15 * 128];
        bf8 ha0 = *reinterpret_cast<const bf8*>(hr + ((16 * lg) ^ swz));
        bf8 ha1 = *reinterpret_cast<const bf8*>(hr + ((64 + 16 * lg) ^ swz));
        acc = __builtin_amdgcn_mfma_f32_16x16x32_bf16(ha0, Ub0, acc, 0, 0, 0);
        acc = __builtin_amdgcn_mfma_f32_16x16x32_bf16(ha1, Ub1, acc, 0, 0, 0);

#pragma unroll
        for (int r = 0; r < 4; ++r) {
            float z = sigm(acc[r] + bgc);
            float c = tanh_fast(acc[r] + buc);
            float w = fmaf(-zs, z, zns);          // zs*(1-z)+ns
            hc[r] = fmaf(z, hc[r], w * c);
        }

        {
            unsigned char* wb = &hb[cur ^ 1][0];
            unsigned pk01 = pk2bf(hc[0], hc[1]);
            unsigned pk23 = pk2bf(hc[2], hc[3]);
            *reinterpret_cast<unsigned short*>(wb + woff[0]) = (unsigned short)pk01;
            *reinterpret_cast<unsigned short*>(wb + woff[1]) = (unsigned short)(pk01 >> 16);
            *reinterpret_cast<unsigned short*>(wb + woff[2]) = (unsigned short)pk23;
            *reinterpret_cast<unsigned short*>(wb + woff[3]) = (unsigned short)(pk23 >> 16);
        }
        __syncthreads();
        cur ^= 1;
        xa0 = xn0; xa1 = xn1;
        xn0 = p0;  xn1 = p1;
    }

    {
        float* op = last0 + ((size_t)(brick * BATCH + batchbase)) * H;
#pragma unroll
        for (int r = 0; r < 4; ++r) {
            int s = 4 * lg + r;
            op[(size_t)s * H + ucol] = hc[r];
        }
    }
}

// Layer 1 + projection, MFMA structure. 16 blocks x 256 thr, 16 batch/block.
__global__ __launch_bounds__(256, 1) void l1_kernel(
    const float* __restrict__ last0,  // [64][256][64]
    const float* __restrict__ W,      // [64][64]
    const float* __restrict__ U,      // [64][64]
    const float* __restrict__ bg,
    const float* __restrict__ bu,
    const float* __restrict__ zeta,
    const float* __restrict__ nu,
    const float* __restrict__ Wout,   // [64][35]
    const float* __restrict__ Bout,   // [35]
    float* __restrict__ out)          // [256][35]
{
    __shared__ unsigned char hb[2][16 * 128];   // bf16 h, swizzled
    __shared__ float hsf[16][H];                // final h staging (4 KB)

    const int tid  = threadIdx.x;
    const int lane = tid & 63;
    const int wn   = __builtin_amdgcn_readfirstlane(tid >> 6);
    const int l15  = lane & 15;
    const int lg   = lane >> 4;

    const int batchbase = blockIdx.x << 4;

    *reinterpret_cast<float2*>(&hb[0][tid * 8]) = make_float2(0.f, 0.f);

    bf8 Wb0, Wb1, Ub0, Ub1;
    const int ucol = wn * 16 + l15;
#pragma unroll
    for (int j = 0; j < 8; ++j) Wb0[j] = f2bf(W[(8 * lg + j) * H + ucol]);
#pragma unroll
    for (int j = 0; j < 8; ++j) Wb1[j] = f2bf(W[(32 + 8 * lg + j) * H + ucol]);
#pragma unroll
    for (int j = 0; j < 8; ++j) Ub0[j] = f2bf(U[(8 * lg + j) * H + ucol]);
#pragma unroll
    for (int j = 0; j < 8; ++j) Ub1[j] = f2bf(U[(32 + 8 * lg + j) * H + ucol]);

    const float bgc = bg[ucol], buc = bu[ucol];
    const float zs  = sigm(zeta[0]);
    const float ns  = sigm(nu[0]);
    const float zns = zs + ns;

    float hc[4] = {0.f, 0.f, 0.f, 0.f};

    // last0 A-source: lane reads rows [batchbase+l15], k chunks 8lg.. and 32+8lg..
    const float* abase = last0 + ((size_t)(batchbase + l15)) * H + 8 * lg;
    const size_t astep = (size_t)BATCH * H;   // t stride

    float4 cA0 = reinterpret_cast<const float4*>(abase)[0];
    float4 cA1 = reinterpret_cast<const float4*>(abase)[1];
    float4 cA2 = reinterpret_cast<const float4*>(abase + 32)[0];
    float4 cA3 = reinterpret_cast<const float4*>(abase + 32)[1];
    float4 nA0 = reinterpret_cast<const float4*>(abase + astep)[0];
    float4 nA1 = reinterpret_cast<const float4*>(abase + astep)[1];
    float4 nA2 = reinterpret_cast<const float4*>(abase + astep + 32)[0];
    float4 nA3 = reinterpret_cast<const float4*>(abase + astep + 32)[1];

    int woff[4];
#pragma unroll
    for (int r = 0; r < 4; ++r) {
        int s = 4 * lg + r;
        woff[r] = s * 128 + ((ucol * 2) ^ ((s & 7) << 4));
    }
    const int swz = (l15 & 7) << 4;

    __syncthreads();

    int cur = 0;
#pragma unroll 1
    for (int t = 0; t < NB; ++t) {
        const int tp = (t + 2 < NB) ? (t + 2) : (NB - 1);
        float4 p0 = reinterpret_cast<const float4*>(abase + (size_t)tp * astep)[0];
        float4 p1 = reinterpret_cast<const float4*>(abase + (size_t)tp * astep)[1];
        float4 p2 = reinterpret_cast<const float4*>(abase + (size_t)tp * astep + 32)[0];
        float4 p3 = reinterpret_cast<const float4*>(abase + (size_t)tp * astep + 32)[1];

        U4BF8 a0, a1;
        a0.u[0] = pk2bf(cA0.x, cA0.y);
        a0.u[1] = pk2bf(cA0.z, cA0.w);
        a0.u[2] = pk2bf(cA1.x, cA1.y);
        a0.u[3] = pk2bf(cA1.z, cA1.w);
        a1.u[0] = pk2bf(cA2.x, cA2.y);
        a1.u[1] = pk2bf(cA2.z, cA2.w);
        a1.u[2] = pk2bf(cA3.x, cA3.y);
        a1.u[3] = pk2bf(cA3.z, cA3.w);

        f32x4 acc = {0.f, 0.f, 0.f, 0.f};
        acc = __builtin_amdgcn_mfma_f32_16x16x32_bf16(a0.v, Wb0, acc, 0, 0, 0);
        acc = __builtin_amdgcn_mfma_f32_16x16x32_bf16(a1.v, Wb1, acc, 0, 0, 0);

        const unsigned char* hr = &hb[cur][l15 * 128];
        bf8 ha0 = *reinterpret_cast<const bf8*>(hr + ((16 * lg) ^ swz));
        bf8 ha1 = *reinterpret_cast<const bf8*>(hr + ((64 + 16 * lg) ^ swz));
        acc = __builtin_amdgcn_mfma_f32_16x16x32_bf16(ha0, Ub0, acc, 0, 0, 0);
        acc = __builtin_amdgcn_mfma_f32_16x16x32_bf16(ha1, Ub1, acc, 0, 0, 0);

#pragma unroll
        for (int r = 0; r < 4; ++r) {
            float z = sigm(acc[r] + bgc);
            float c = tanh_fast(acc[r] + buc);
            float w = fmaf(-zs, z, zns);
            hc[r] = fmaf(z, hc[r], w * c);
        }

        {
            unsigned char* wb = &hb[cur ^ 1][0];
            unsigned pk01 = pk2bf(hc[0], hc[1]);
            unsigned pk23 = pk2bf(hc[2], hc[3]);
            *reinterpret_cast<unsigned short*>(wb + woff[0]) = (unsigned short)pk01;
            *reinterpret_cast<unsigned short*>(wb + woff[1]) = (unsigned short)(pk01 >> 16);
            *reinterpret_cast<unsigned short*>(wb + woff[2]) = (unsigned short)pk23;
            *reinterpret_cast<unsigned short*>(wb + woff[3]) = (unsigned short)(pk23 >> 16);
        }
        __syncthreads();
        cur ^= 1;
        cA0 = nA0; cA1 = nA1; cA2 = nA2; cA3 = nA3;
        nA0 = p0;  nA1 = p1;  nA2 = p2;  nA3 = p3;
    }

    // stage final h, then fused projection
#pragma unroll
    for (int r = 0; r < 4; ++r) hsf[4 * lg + r][ucol] = hc[r];
    __syncthreads();

    for (int p = tid; p < 16 * OUTD; p += 256) {
        int s = p / OUTD;
        int o = p - s * OUTD;
        float a = Bout[o];
#pragma unroll
        for (int u = 0; u < H; ++u) a = fmaf(hsf[s][u], Wout[u * OUTD + o], a);
        out[(size_t)(batchbase + s) * OUTD + o] = a;
    }
}

extern "C" void kernel_launch(void* const* d_in, const int* in_sizes, int n_in,
                              void* d_out, int out_size, void* d_ws, size_t ws_size,
                              hipStream_t stream) {
    const float* x    = (const float*)d_in[0];
    const float* W0   = (const float*)d_in[2];
    const float* U0   = (const float*)d_in[3];
    const float* bg0  = (const float*)d_in[4];
    const float* bu0  = (const float*)d_in[5];
    const float* z0   = (const float*)d_in[6];
    const float* n0   = (const float*)d_in[7];
    const float* W1   = (const float*)d_in[8];
    const float* U1   = (const float*)d_in[9];
    const float* bg1  = (const float*)d_in[10];
    const float* bu1  = (const float*)d_in[11];
    const float* z1   = (const float*)d_in[12];
    const float* n1   = (const float*)d_in[13];
    const float* Wout = (const float*)d_in[14];
    const float* Bout = (const float*)d_in[15];
    float* out = (float*)d_out;

    float* last0 = (float*)d_ws;   // 4 MB scratch

    l0_kernel<<<1024, 256, 0, stream>>>(x, W0, U0, bg0, bu0, z0, n0, last0);
    l1_kernel<<<16, 256, 0, stream>>>(last0, W1, U1, bg1, bu1, z1, n1, Wout, Bout, out);
}

// Round 7
// 79.290 us; speedup vs baseline: 1.1968x; 1.1968x over previous
//
#include <hip/hip_runtime.h>
#include <hip/hip_bf16.h>

// FastGRNN 2-layer (SRNN2). T=2048, B=256, D=32, H0=H1=64, O=35, brick=32.
// Layer 0: bf16 MFMA, fp32 accum + fp32 state. 1024 blocks x 256 thr (4 waves),
//   16 seqs/block, wave wn owns unit tile [16wn,16wn+16). 3 mfma/step/wave,
//   h via double-buffered XOR-swizzled bf16 LDS, x prefetch 2 steps.
// Layer 1: same MFMA structure, 16 blocks x 4 waves, 16 batch/block, 64 steps.
// KEY (round 7): per-step barriers are raw {s_waitcnt lgkmcnt(0); s_barrier}
//   in ONE asm block -> global prefetch loads stay in flight across barriers
//   (no compiler vmcnt(0) drain, the T4 counted-vmcnt effect). LDS ordering is
//   preserved: every wave drains lgkm before the barrier; h is double-buffered.

#define NB    64
#define BS    32
#define BATCH 256
#define D0    32
#define H     64
#define OUTD  35

typedef short  bf8   __attribute__((ext_vector_type(8)));
typedef float  f32x4 __attribute__((ext_vector_type(4)));

__device__ __forceinline__ float rcp_fast(float x) {
    return __builtin_amdgcn_rcpf(x);
}
__device__ __forceinline__ float sigm(float x) {
    return rcp_fast(1.0f + __expf(-x));
}
// tanh(x) = 2*sigm(2x)-1 : 5 VALU, NaN-free
__device__ __forceinline__ float tanh_fast(float x) {
    float q = rcp_fast(1.0f + __expf(-2.0f * x));
    return fmaf(2.0f, q, -1.0f);
}
__device__ __forceinline__ short f2bf(float f) {   // init-path only
    __hip_bfloat16 b = __float2bfloat16(f);
    return __builtin_bit_cast(short, b);
}
// packed pair -> v_cvt_pk_bf16_f32 (lo in bits[15:0])
__device__ __forceinline__ unsigned pk2bf(float lo, float hi) {
    __hip_bfloat162 h2 = __float22bfloat162_rn(make_float2(lo, hi));
    unsigned r;
    __builtin_memcpy(&r, &h2, 4);
    return r;
}
// LDS-only barrier: waits ds ops, leaves global loads (vmcnt) outstanding.
// Single asm block: nothing can be scheduled between the wait and s_barrier,
// and the memory clobber stops later LDS ops hoisting above it.
__device__ __forceinline__ void lds_barrier() {
    asm volatile("s_waitcnt lgkmcnt(0)\n\ts_barrier" ::: "memory");
}

union U4BF8 { unsigned u[4]; bf8 v; };

__global__ __launch_bounds__(256, 4) void l0_kernel(
    const float* __restrict__ x,     // [2048][256][32]
    const float* __restrict__ W,     // [32][64]
    const float* __restrict__ U,     // [64][64]
    const float* __restrict__ bg,
    const float* __restrict__ bu,
    const float* __restrict__ zeta,
    const float* __restrict__ nu,
    float* __restrict__ last0)       // [64*256][64]
{
    __shared__ unsigned char hb[2][16 * 128];   // bf16 h, bytes ^((seq&7)<<4)

    const int tid  = threadIdx.x;
    const int lane = tid & 63;
    const int wn   = __builtin_amdgcn_readfirstlane(tid >> 6);
    const int l15  = lane & 15;
    const int lg   = lane >> 4;

    const int brick     = blockIdx.x >> 4;
    const int batchbase = (blockIdx.x & 15) << 4;

    *reinterpret_cast<float2*>(&hb[0][tid * 8]) = make_float2(0.f, 0.f);

    bf8 Wb, Ub0, Ub1;
    const int ucol = wn * 16 + l15;
#pragma unroll
    for (int j = 0; j < 8; ++j) Wb[j]  = f2bf(W[(8 * lg + j) * H + ucol]);
#pragma unroll
    for (int j = 0; j < 8; ++j) Ub0[j] = f2bf(U[(8 * lg + j) * H + ucol]);
#pragma unroll
    for (int j = 0; j < 8; ++j) Ub1[j] = f2bf(U[(32 + 8 * lg + j) * H + ucol]);

    const float bgc = bg[ucol], buc = bu[ucol];
    const float zs  = sigm(zeta[0]);
    const float ns  = sigm(nu[0]);
    const float zns = zs + ns;

    float hc[4] = {0.f, 0.f, 0.f, 0.f};

    const float* xbase = x + ((size_t)(brick * BS) * BATCH + batchbase + l15) * D0 + 8 * lg;
    const size_t xstep = (size_t)BATCH * D0;

    float4 xa0 = reinterpret_cast<const float4*>(xbase)[0];
    float4 xa1 = reinterpret_cast<const float4*>(xbase)[1];
    float4 xn0 = reinterpret_cast<const float4*>(xbase + xstep)[0];
    float4 xn1 = reinterpret_cast<const float4*>(xbase + xstep)[1];

    int woff[4];
#pragma unroll
    for (int r = 0; r < 4; ++r) {
        int s = 4 * lg + r;
        woff[r] = s * 128 + ((ucol * 2) ^ ((s & 7) << 4));
    }
    const int swz = (l15 & 7) << 4;

    __syncthreads();

    int cur = 0;
#pragma unroll 1
    for (int t = 0; t < BS; ++t) {
        const int tp = (t + 2 < BS) ? (t + 2) : (BS - 1);
        float4 p0 = reinterpret_cast<const float4*>(xbase + (size_t)tp * xstep)[0];
        float4 p1 = reinterpret_cast<const float4*>(xbase + (size_t)tp * xstep)[1];

        U4BF8 xp;
        xp.u[0] = pk2bf(xa0.x, xa0.y);
        xp.u[1] = pk2bf(xa0.z, xa0.w);
        xp.u[2] = pk2bf(xa1.x, xa1.y);
        xp.u[3] = pk2bf(xa1.z, xa1.w);

        f32x4 acc = {0.f, 0.f, 0.f, 0.f};
        acc = __builtin_amdgcn_mfma_f32_16x16x32_bf16(xp.v, Wb, acc, 0, 0, 0);

        const unsigned char* hr = &hb[cur][l15 * 128];
        bf8 ha0 = *reinterpret_cast<const bf8*>(hr + ((16 * lg) ^ swz));
        bf8 ha1 = *reinterpret_cast<const bf8*>(hr + ((64 + 16 * lg) ^ swz));
        acc = __builtin_amdgcn_mfma_f32_16x16x32_bf16(ha0, Ub0, acc, 0, 0, 0);
        acc = __builtin_amdgcn_mfma_f32_16x16x32_bf16(ha1, Ub1, acc, 0, 0, 0);

#pragma unroll
        for (int r = 0; r < 4; ++r) {
            float z = sigm(acc[r] + bgc);
            float c = tanh_fast(acc[r] + buc);
            float w = fmaf(-zs, z, zns);          // zs*(1-z)+ns
            hc[r] = fmaf(z, hc[r], w * c);
        }

        {
            unsigned char* wb = &hb[cur ^ 1][0];
            unsigned pk01 = pk2bf(hc[0], hc[1]);
            unsigned pk23 = pk2bf(hc[2], hc[3]);
            *reinterpret_cast<unsigned short*>(wb + woff[0]) = (unsigned short)pk01;
            *reinterpret_cast<unsigned short*>(wb + woff[1]) = (unsigned short)(pk01 >> 16);
            *reinterpret_cast<unsigned short*>(wb + woff[2]) = (unsigned short)pk23;
            *reinterpret_cast<unsigned short*>(wb + woff[3]) = (unsigned short)(pk23 >> 16);
        }
        lds_barrier();     // ds drained; x prefetch stays in flight
        cur ^= 1;
        xa0 = xn0; xa1 = xn1;
        xn0 = p0;  xn1 = p1;
    }

    {
        float* op = last0 + ((size_t)(brick * BATCH + batchbase)) * H;
#pragma unroll
        for (int r = 0; r < 4; ++r) {
            int s = 4 * lg + r;
            op[(size_t)s * H + ucol] = hc[r];
        }
    }
}

// Layer 1 + projection, MFMA structure. 16 blocks x 256 thr, 16 batch/block.
__global__ __launch_bounds__(256, 1) void l1_kernel(
    const float* __restrict__ last0,  // [64][256][64]
    const float* __restrict__ W,      // [64][64]
    const float* __restrict__ U,      // [64][64]
    const float* __restrict__ bg,
    const float* __restrict__ bu,
    const float* __restrict__ zeta,
    const float* __restrict__ nu,
    const float* __restrict__ Wout,   // [64][35]
    const float* __restrict__ Bout,   // [35]
    float* __restrict__ out)          // [256][35]
{
    __shared__ unsigned char hb[2][16 * 128];   // bf16 h, swizzled
    __shared__ float hsf[16][H];                // final h staging

    const int tid  = threadIdx.x;
    const int lane = tid & 63;
    const int wn   = __builtin_amdgcn_readfirstlane(tid >> 6);
    const int l15  = lane & 15;
    const int lg   = lane >> 4;

    const int batchbase = blockIdx.x << 4;

    *reinterpret_cast<float2*>(&hb[0][tid * 8]) = make_float2(0.f, 0.f);

    bf8 Wb0, Wb1, Ub0, Ub1;
    const int ucol = wn * 16 + l15;
#pragma unroll
    for (int j = 0; j < 8; ++j) Wb0[j] = f2bf(W[(8 * lg + j) * H + ucol]);
#pragma unroll
    for (int j = 0; j < 8; ++j) Wb1[j] = f2bf(W[(32 + 8 * lg + j) * H + ucol]);
#pragma unroll
    for (int j = 0; j < 8; ++j) Ub0[j] = f2bf(U[(8 * lg + j) * H + ucol]);
#pragma unroll
    for (int j = 0; j < 8; ++j) Ub1[j] = f2bf(U[(32 + 8 * lg + j) * H + ucol]);

    const float bgc = bg[ucol], buc = bu[ucol];
    const float zs  = sigm(zeta[0]);
    const float ns  = sigm(nu[0]);
    const float zns = zs + ns;

    float hc[4] = {0.f, 0.f, 0.f, 0.f};

    const float* abase = last0 + ((size_t)(batchbase + l15)) * H + 8 * lg;
    const size_t astep = (size_t)BATCH * H;

    float4 cA0 = reinterpret_cast<const float4*>(abase)[0];
    float4 cA1 = reinterpret_cast<const float4*>(abase)[1];
    float4 cA2 = reinterpret_cast<const float4*>(abase + 32)[0];
    float4 cA3 = reinterpret_cast<const float4*>(abase + 32)[1];
    float4 nA0 = reinterpret_cast<const float4*>(abase + astep)[0];
    float4 nA1 = reinterpret_cast<const float4*>(abase + astep)[1];
    float4 nA2 = reinterpret_cast<const float4*>(abase + astep + 32)[0];
    float4 nA3 = reinterpret_cast<const float4*>(abase + astep + 32)[1];

    int woff[4];
#pragma unroll
    for (int r = 0; r < 4; ++r) {
        int s = 4 * lg + r;
        woff[r] = s * 128 + ((ucol * 2) ^ ((s & 7) << 4));
    }
    const int swz = (l15 & 7) << 4;

    __syncthreads();

    int cur = 0;
#pragma unroll 1
    for (int t = 0; t < NB; ++t) {
        const int tp = (t + 2 < NB) ? (t + 2) : (NB - 1);
        float4 p0 = reinterpret_cast<const float4*>(abase + (size_t)tp * astep)[0];
        float4 p1 = reinterpret_cast<const float4*>(abase + (size_t)tp * astep)[1];
        float4 p2 = reinterpret_cast<const float4*>(abase + (size_t)tp * astep + 32)[0];
        float4 p3 = reinterpret_cast<const float4*>(abase + (size_t)tp * astep + 32)[1];

        U4BF8 a0, a1;
        a0.u[0] = pk2bf(cA0.x, cA0.y);
        a0.u[1] = pk2bf(cA0.z, cA0.w);
        a0.u[2] = pk2bf(cA1.x, cA1.y);
        a0.u[3] = pk2bf(cA1.z, cA1.w);
        a1.u[0] = pk2bf(cA2.x, cA2.y);
        a1.u[1] = pk2bf(cA2.z, cA2.w);
        a1.u[2] = pk2bf(cA3.x, cA3.y);
        a1.u[3] = pk2bf(cA3.z, cA3.w);

        f32x4 acc = {0.f, 0.f, 0.f, 0.f};
        acc = __builtin_amdgcn_mfma_f32_16x16x32_bf16(a0.v, Wb0, acc, 0, 0, 0);
        acc = __builtin_amdgcn_mfma_f32_16x16x32_bf16(a1.v, Wb1, acc, 0, 0, 0);

        const unsigned char* hr = &hb[cur][l15 * 128];
        bf8 ha0 = *reinterpret_cast<const bf8*>(hr + ((16 * lg) ^ swz));
        bf8 ha1 = *reinterpret_cast<const bf8*>(hr + ((64 + 16 * lg) ^ swz));
        acc = __builtin_amdgcn_mfma_f32_16x16x32_bf16(ha0, Ub0, acc, 0, 0, 0);
        acc = __builtin_amdgcn_mfma_f32_16x16x32_bf16(ha1, Ub1, acc, 0, 0, 0);

#pragma unroll
        for (int r = 0; r < 4; ++r) {
            float z = sigm(acc[r] + bgc);
            float c = tanh_fast(acc[r] + buc);
            float w = fmaf(-zs, z, zns);
            hc[r] = fmaf(z, hc[r], w * c);
        }

        {
            unsigned char* wb = &hb[cur ^ 1][0];
            unsigned pk01 = pk2bf(hc[0], hc[1]);
            unsigned pk23 = pk2bf(hc[2], hc[3]);
            *reinterpret_cast<unsigned short*>(wb + woff[0]) = (unsigned short)pk01;
            *reinterpret_cast<unsigned short*>(wb + woff[1]) = (unsigned short)(pk01 >> 16);
            *reinterpret_cast<unsigned short*>(wb + woff[2]) = (unsigned short)pk23;
            *reinterpret_cast<unsigned short*>(wb + woff[3]) = (unsigned short)(pk23 >> 16);
        }
        lds_barrier();     // ds drained; last0 prefetch stays in flight
        cur ^= 1;
        cA0 = nA0; cA1 = nA1; cA2 = nA2; cA3 = nA3;
        nA0 = p0;  nA1 = p1;  nA2 = p2;  nA3 = p3;
    }

    // stage final h, then fused projection
#pragma unroll
    for (int r = 0; r < 4; ++r) hsf[4 * lg + r][ucol] = hc[r];
    __syncthreads();

    for (int p = tid; p < 16 * OUTD; p += 256) {
        int s = p / OUTD;
        int o = p - s * OUTD;
        float a = Bout[o];
#pragma unroll
        for (int u = 0; u < H; ++u) a = fmaf(hsf[s][u], Wout[u * OUTD + o], a);
        out[(size_t)(batchbase + s) * OUTD + o] = a;
    }
}

extern "C" void kernel_launch(void* const* d_in, const int* in_sizes, int n_in,
                              void* d_out, int out_size, void* d_ws, size_t ws_size,
                              hipStream_t stream) {
    const float* x    = (const float*)d_in[0];
    const float* W0   = (const float*)d_in[2];
    const float* U0   = (const float*)d_in[3];
    const float* bg0  = (const float*)d_in[4];
    const float* bu0  = (const float*)d_in[5];
    const float* z0   = (const float*)d_in[6];
    const float* n0   = (const float*)d_in[7];
    const float* W1   = (const float*)d_in[8];
    const float* U1   = (const float*)d_in[9];
    const float* bg1  = (const float*)d_in[10];
    const float* bu1  = (const float*)d_in[11];
    const float* z1   = (const float*)d_in[12];
    const float* n1   = (const float*)d_in[13];
    const float* Wout = (const float*)d_in[14];
    const float* Bout = (const float*)d_in[15];
    float* out = (float*)d_out;

    float* last0 = (float*)d_ws;   // 4 MB scratch

    l0_kernel<<<1024, 256, 0, stream>>>(x, W0, U0, bg0, bu0, z0, n0, last0);
    l1_kernel<<<16, 256, 0, stream>>>(last0, W1, U1, bg1, bu1, z1, n1, Wout, Bout, out);
}